// Round 4
// baseline (658.808 us; speedup 1.0000x reference)
//
#include <hip/hip_runtime.h>

// Problem constants (fixed by the reference file).
#define SAMPLES 16
#define NEVENTS (1 << 20)          // 1048576
#define FRAMES  16
#define FSZ     128
#define WIN     (NEVENTS / FRAMES) // 65536 events per frame
#define BINS    (FSZ * FSZ)        // 16384 (y*128 + x)
#define PLANES  2
#define SLICE   (PLANES * BINS)    // 32768 floats per (frame, sample)
#define TPB     1024
#define CHUNKS  (WIN / (4 * TPB))  // 16 v4-chunks per thread (64 events)
#define OUTFLOATS ((size_t)FRAMES * SAMPLES * SLICE)   // 8.4M floats
#define OUTBYTES  (OUTFLOATS * sizeof(float))          // 33.5 MB

// clang ext-vector types (true vector types: accepted by
// __builtin_nontemporal_{load,store}, support .x/.y/.z/.w).
typedef float v4f __attribute__((ext_vector_type(4)));
typedef int   v4i __attribute__((ext_vector_type(4)));

// R3 post-mortem: three load/atomic schedules (interleave, ping-pong,
// prep+burst) all land at kernel ~100us == 240K cy/CU for 1024 wave64
// ds_add_f32 -> ~230 cy per scattered wave-atomic (~3.5 cy/lane-op,
// serialized in the DS unit; NOT bank-conflict-driven, which would predict
// ~10-15us). The DS atomic pipe is a fixed-rate serial resource; the only
// lever is moving atomics OFF it. This revision: hybrid split — even chunks
// -> LDS atomics (DS pipe), odd chunks -> global_atomic_add_f32 with
// WORKGROUP scope into a zeroed workspace slice (executes in the XCD-local
// L2; exactly one block touches each slice, so workgroup scope suffices and
// no device-scope L3 round-trip is forced). Epilogue: out = lds + ws.
// DS lane-ops halve; TCC atomics run on the independent VMEM path.

// Compute plane|y|x element offsets and |v| for 4 events (literal indices
// only -> SROA keeps off/av in registers).
__device__ __forceinline__ void prep4(v4f v, v4i xv, v4i yv, int* off, float* av) {
    // plane bit: 1 if v>=0 (pos plane, +BINS=+1<<14), 0 if v<0 (neg plane).
    // v==+-0 adds 0.0f -> no-op either way. y<128, x<128 -> OR is exact.
    const unsigned ux = __float_as_uint(v.x), uy = __float_as_uint(v.y),
                   uz = __float_as_uint(v.z), uw = __float_as_uint(v.w);
    off[0] = (int)((((~ux) >> 31) << 14) | ((unsigned)yv.x << 7) | (unsigned)xv.x);
    off[1] = (int)((((~uy) >> 31) << 14) | ((unsigned)yv.y << 7) | (unsigned)xv.y);
    off[2] = (int)((((~uz) >> 31) << 14) | ((unsigned)yv.z << 7) | (unsigned)xv.z);
    off[3] = (int)((((~uw) >> 31) << 14) | ((unsigned)yv.w << 7) | (unsigned)xv.w);
    av[0] = __builtin_fabsf(v.x);
    av[1] = __builtin_fabsf(v.y);
    av[2] = __builtin_fabsf(v.z);
    av[3] = __builtin_fabsf(v.w);
}

__global__ __launch_bounds__(TPB) void frame_accum_hybrid(
    const float* __restrict__ ev,   // [S, N] event_values
    const int*   __restrict__ idx,  // [S, 3, N]; only [0,1,:] (x), [0,2,:] (y) used
    float*       __restrict__ ws,   // [F, S, 2, Y, X] scratch, pre-zeroed
    float*       __restrict__ out)  // [F, S, 2, Y, X]
{
    extern __shared__ float lds[];  // [2][BINS]: plane 0 = neg, plane 1 = pos
    const int tid = threadIdx.x;
    const int s = blockIdx.x & (SAMPLES - 1);
    const int f = blockIdx.x >> 4;

    // Zero the private LDS accumulator.
    v4f* lds4 = (v4f*)lds;
    const v4f zero4 = (v4f)(0.f);
#pragma unroll
    for (int i = 0; i < (SLICE / 4) / TPB; ++i)   // 8 iters
        lds4[i * TPB + tid] = zero4;
    __syncthreads();

    // This block's event slice: events [f*WIN, (f+1)*WIN), sample s.
    const v4f* ev4 = (const v4f*)(ev  + (size_t)s * NEVENTS + (size_t)f * WIN);
    const v4i* x4  = (const v4i*)(idx + (size_t)NEVENTS      + (size_t)f * WIN); // indices[0,1,:]
    const v4i* y4  = (const v4i*)(idx + (size_t)2 * NEVENTS  + (size_t)f * WIN); // indices[0,2,:]
    float* wsp = ws + (size_t)(f * SAMPLES + s) * SLICE;   // exclusive slice

#pragma unroll 4
    for (int c = 0; c < CHUNKS; ++c) {
        const int base = c * TPB + tid;
        const v4f v  = __builtin_nontemporal_load(&ev4[base]);
        const v4i xv = x4[base];
        const v4i yv = y4[base];
        int off[4]; float av[4];
        prep4(v, xv, yv, off, av);
        if (c & 1) {
            // VMEM/TCC pipe: workgroup-scope global f32 atomic -> XCD-local L2.
#pragma unroll
            for (int k = 0; k < 4; ++k)
                (void)__hip_atomic_fetch_add(&wsp[off[k]], av[k],
                                             __ATOMIC_RELAXED,
                                             __HIP_MEMORY_SCOPE_WORKGROUP);
        } else {
            // DS pipe: LDS atomics (load now halved).
#pragma unroll
            for (int k = 0; k < 4; ++k)
                atomicAdd(&lds[off[k]], av[k]);
        }
    }
    __threadfence_block();   // make ws atomics visible to this block's reads
    __syncthreads();         // also drains vmcnt/lgkmcnt for all waves

    // Epilogue: out = lds + ws (both halves), coalesced v4. out is write-once
    // -> nontemporal; ws read hits this XCD's L2 (just written by atomics).
    const v4f* ws4 = (const v4f*)wsp;
    v4f* op4 = (v4f*)(out + (size_t)(f * SAMPLES + s) * SLICE);
#pragma unroll
    for (int i = 0; i < (SLICE / 4) / TPB; ++i) {  // 8 iters
        const v4f r = lds4[i * TPB + tid] + ws4[i * TPB + tid];
        __builtin_nontemporal_store(r, &op4[i * TPB + tid]);
    }
}

// Fallback (ws too small): prior best pure-LDS kernel, ~100us.
__global__ __launch_bounds__(TPB) void frame_accum_ldsonly(
    const float* __restrict__ ev,
    const int*   __restrict__ idx,
    float*       __restrict__ out)
{
    extern __shared__ float lds[];
    const int tid = threadIdx.x;
    const int s = blockIdx.x & (SAMPLES - 1);
    const int f = blockIdx.x >> 4;

    v4f* lds4 = (v4f*)lds;
    const v4f zero4 = (v4f)(0.f);
#pragma unroll
    for (int i = 0; i < (SLICE / 4) / TPB; ++i)
        lds4[i * TPB + tid] = zero4;
    __syncthreads();

    const v4f* ev4 = (const v4f*)(ev  + (size_t)s * NEVENTS + (size_t)f * WIN);
    const v4i* x4  = (const v4i*)(idx + (size_t)NEVENTS      + (size_t)f * WIN);
    const v4i* y4  = (const v4i*)(idx + (size_t)2 * NEVENTS  + (size_t)f * WIN);

#pragma unroll 4
    for (int c = 0; c < CHUNKS; ++c) {
        const int base = c * TPB + tid;
        const v4f v  = __builtin_nontemporal_load(&ev4[base]);
        const v4i xv = x4[base];
        const v4i yv = y4[base];
        int off[4]; float av[4];
        prep4(v, xv, yv, off, av);
#pragma unroll
        for (int k = 0; k < 4; ++k)
            atomicAdd(&lds[off[k]], av[k]);
    }
    __syncthreads();

    v4f* op4 = (v4f*)(out + (size_t)(f * SAMPLES + s) * SLICE);
#pragma unroll
    for (int i = 0; i < (SLICE / 4) / TPB; ++i)
        __builtin_nontemporal_store(lds4[i * TPB + tid], &op4[i * TPB + tid]);
}

extern "C" void kernel_launch(void* const* d_in, const int* in_sizes, int n_in,
                              void* d_out, int out_size, void* d_ws, size_t ws_size,
                              hipStream_t stream) {
    const float* ev  = (const float*)d_in[0];
    const int*   idx = (const int*)d_in[1];
    // d_in[2] = use_soft, fixed 0 (hard path) -> ignored.
    float* out = (float*)d_out;

    if (d_ws != nullptr && ws_size >= OUTBYTES) {
        float* ws = (float*)d_ws;
        // Zero the atomic scratch (graph-captureable, stream-ordered).
        (void)hipMemsetAsync(ws, 0, OUTBYTES, stream);
        (void)hipFuncSetAttribute((const void*)frame_accum_hybrid,
                                  hipFuncAttributeMaxDynamicSharedMemorySize,
                                  SLICE * (int)sizeof(float));
        frame_accum_hybrid<<<FRAMES * SAMPLES, TPB, SLICE * sizeof(float), stream>>>(
            ev, idx, ws, out);
    } else {
        (void)hipFuncSetAttribute((const void*)frame_accum_ldsonly,
                                  hipFuncAttributeMaxDynamicSharedMemorySize,
                                  SLICE * (int)sizeof(float));
        frame_accum_ldsonly<<<FRAMES * SAMPLES, TPB, SLICE * sizeof(float), stream>>>(
            ev, idx, out);
    }
}

// Round 6
// 341.192 us; speedup vs baseline: 1.9309x; 1.9309x over previous
//
#include <hip/hip_runtime.h>

// Problem constants (fixed by the reference file).
#define SAMPLES 16
#define NEVENTS (1 << 20)          // 1048576
#define FRAMES  16
#define FSZ     128
#define WIN     (NEVENTS / FRAMES) // 65536 events per frame
#define BINS    (FSZ * FSZ)        // 16384 (y*128 + x)
#define PLANES  2
#define SLICE   (PLANES * BINS)    // 32768 floats per (frame, sample)
#define TPB     1024
#define CHUNKS  (WIN / (4 * TPB))  // 16 v4-chunks per thread (64 events)

// clang ext-vector types (true vector types: accepted by
// __builtin_nontemporal_{load,store}, support .x/.y/.z/.w).
typedef float v4f __attribute__((ext_vector_type(4)));
typedef int   v4i __attribute__((ext_vector_type(4)));

// R5 post-mortem: inline-asm ds_add_f32 gave absmax 2.75 — a FRACTION of
// bins short a few events. Cause: SIInsertWaitcnts doesn't model inline-asm
// DS ops, so the final __syncthreads() emitted s_barrier WITHOUT
// s_waitcnt lgkmcnt(0); waves crossed the barrier with atomics still queued
// in the DS unit and the epilogue reads raced them (same family as the
// guide's rule #18: asm memory ops must carry their own waitcnt).
// Fix: explicit "s_waitcnt lgkmcnt(0)" asm before the barrier (every wave
// drains its own DS queue; barrier then guarantees global visibility), and
// derive the 32-bit LDS address via a real addrspacecast to AS3.
//
// Structure otherwise = measured-best baseline: ONE kernel, one block per
// (frame, sample); block owns out[f,s,:,:,:] (128 KB LDS) exclusively ->
// pure LDS privatization; input read-once, output written-once.

typedef __attribute__((address_space(3))) float lds_f32;

__device__ __forceinline__ unsigned lds_addr(float* p) {
    // generic -> LDS(AS3) addrspacecast, then to the 32-bit byte offset the
    // DS unit consumes. Compiler-correct equivalent of pointer truncation.
    return (unsigned)(size_t)(lds_f32*)p;
}

// Compute plane|y|x BYTE offsets and |v| for 4 events (literal indices only
// -> SROA keeps off/av in registers).
__device__ __forceinline__ void prep4(v4f v, v4i xv, v4i yv, int* off, float* av) {
    // plane bit: 1 if v>=0 (pos plane, +BINS), 0 if v<0 (neg plane).
    // v==+-0 adds 0.0f -> no-op either way. y<128, x<128 -> OR is exact.
    const unsigned ux = __float_as_uint(v.x), uy = __float_as_uint(v.y),
                   uz = __float_as_uint(v.z), uw = __float_as_uint(v.w);
    off[0] = (int)(((((~ux) >> 31) << 14) | ((unsigned)yv.x << 7) | (unsigned)xv.x) << 2);
    off[1] = (int)(((((~uy) >> 31) << 14) | ((unsigned)yv.y << 7) | (unsigned)xv.y) << 2);
    off[2] = (int)(((((~uz) >> 31) << 14) | ((unsigned)yv.z << 7) | (unsigned)xv.z) << 2);
    off[3] = (int)(((((~uw) >> 31) << 14) | ((unsigned)yv.w << 7) | (unsigned)xv.w) << 2);
    av[0] = __builtin_fabsf(v.x);
    av[1] = __builtin_fabsf(v.y);
    av[2] = __builtin_fabsf(v.z);
    av[3] = __builtin_fabsf(v.w);
}

__global__ __launch_bounds__(TPB) void frame_accum_kernel(
    const float* __restrict__ ev,   // [S, N] event_values
    const int*   __restrict__ idx,  // [S, 3, N]; only [0,1,:] (x), [0,2,:] (y) used
    float*       __restrict__ out)  // [F, S, 2, Y, X]
{
    extern __shared__ float lds[];  // [2][BINS]: plane 0 = neg, plane 1 = pos
    const int tid = threadIdx.x;
    const int s = blockIdx.x & (SAMPLES - 1);
    const int f = blockIdx.x >> 4;

    // Zero the private accumulator.
    v4f* lds4 = (v4f*)lds;
    const v4f zero4 = (v4f)(0.f);
#pragma unroll
    for (int i = 0; i < (SLICE / 4) / TPB; ++i)   // 8 iters
        lds4[i * TPB + tid] = zero4;
    __syncthreads();

    const unsigned lbase = lds_addr(lds);

    // This block's event slice: events [f*WIN, (f+1)*WIN), sample s.
    const v4f* ev4 = (const v4f*)(ev  + (size_t)s * NEVENTS + (size_t)f * WIN);
    const v4i* x4  = (const v4i*)(idx + (size_t)NEVENTS      + (size_t)f * WIN); // indices[0,1,:]
    const v4i* y4  = (const v4i*)(idx + (size_t)2 * NEVENTS  + (size_t)f * WIN); // indices[0,2,:]

#pragma unroll 4
    for (int c = 0; c < CHUNKS; ++c) {
        const int base = c * TPB + tid;
        const v4f v  = __builtin_nontemporal_load(&ev4[base]);
        const v4i xv = x4[base];
        const v4i yv = y4[base];
        int off[4]; float av[4];
        prep4(v, xv, yv, off, av);
        // NATIVE LDS f32 atomic add (no return) — bypasses any CAS-loop
        // lowering of atomicAdd(float*).
#pragma unroll
        for (int k = 0; k < 4; ++k) {
            const unsigned a = lbase + (unsigned)off[k];
            asm volatile("ds_add_f32 %0, %1" :: "v"(a), "v"(av[k]) : "memory");
        }
    }
    // The compiler does NOT track inline-asm DS ops: drain them explicitly
    // before the barrier (R5 correctness fix). After s_barrier, all waves'
    // atomics are committed to LDS.
    asm volatile("s_waitcnt lgkmcnt(0)" ::: "memory");
    __syncthreads();

    // Coalesced write of the exclusive slice: out[f, s, p, y, x]; LDS layout
    // (neg plane first) matches the output plane order exactly. Nontemporal:
    // out is write-once, never re-read.
    v4f* op4 = (v4f*)(out + (size_t)(f * SAMPLES + s) * SLICE);
#pragma unroll
    for (int i = 0; i < (SLICE / 4) / TPB; ++i)   // 8 iters
        __builtin_nontemporal_store(lds4[i * TPB + tid], &op4[i * TPB + tid]);
}

extern "C" void kernel_launch(void* const* d_in, const int* in_sizes, int n_in,
                              void* d_out, int out_size, void* d_ws, size_t ws_size,
                              hipStream_t stream) {
    const float* ev  = (const float*)d_in[0];
    const int*   idx = (const int*)d_in[1];
    // d_in[2] = use_soft, fixed 0 (hard path) -> ignored.
    float* out = (float*)d_out;

    // 128 KB dynamic LDS per block; gfx950 GROUP segment is 160 KB/CU.
    (void)hipFuncSetAttribute((const void*)frame_accum_kernel,
                              hipFuncAttributeMaxDynamicSharedMemorySize,
                              SLICE * (int)sizeof(float));

    frame_accum_kernel<<<FRAMES * SAMPLES, TPB, SLICE * sizeof(float), stream>>>(
        ev, idx, out);
}